// Round 14
// baseline (61.772 us; speedup 1.0000x reference)
//
#include <hip/hip_runtime.h>
#include <hip/hip_bf16.h>
#include <math.h>

typedef __attribute__((ext_vector_type(4)))  short short4v;
typedef __attribute__((ext_vector_type(8)))  short short8;
typedef __attribute__((ext_vector_type(16))) float f32x16;

#define B_   2
#define N_   768
#define CN_  384
#define H_   12
#define EPS_ 1e-7f
// log2e-scaled constants (softmax runs in exp2 domain; scaling by log2e folds
// into every logit source, p-values mathematically unchanged)
#define QSCALE_  0.20823509193522788f   // (1/sqrt(48)) * log2e
#define HWSCALE_ 0.19632592787762333f   // sqrt(1/54) * log2e
#define INF2_    144269.50408889634f    // 100000 * log2e

#define EXP2F(x) __builtin_amdgcn_exp2f(x)

// ---------------- workspace layout (f32-slot offsets) ----------------
// PROJP f32 [1536][576]       at 0        (point-proj columns + bias; dead after pack3)
// OPg bf16 [1536][288]        at 1032192
// CATT bf16 [48][72][32][8]   at 1253376  (chunk-interleaved; chunks 0..23 = o-part,
//     written directly by attn2's merge; chunks 24..71 built in out_fused2 LDS)
// Qf  bf16 [24][768][32]      at 1769472  (log2e-scaled q / qp)
// Kf  bf16 [24][768][32]      at 2064384  (kc slots log2e-scaled)
// VtT bf16 [24][24][64][32]   at 2359296  (tile-interleaved; d rows 40..63
//     never written: garbage confined to discarded acc1 regs 4..15)
// SB  bf16 [1536][384]        at 2949120
// WB  bf16 [1152][384]        at 3244032
// WOBT bf16 [12][72][32][8]   at 3465216  (chunk-interleaved w_out)
// MBf f32 [2][24][24][64][16] at 3575808  (fragment-order mask bias, log2e-scaled)
#define OFF_PROJP 0
#define OFF_OP    1032192
#define OFF_CAT   1253376
#define OFF_QF    1769472
#define OFF_KF    2064384
#define OFF_VT    2359296
#define OFF_SB    2949120
#define OFF_WB    3244032
#define OFF_WOB   3465216
#define OFF_MB    3575808

__device__ inline float b2f(unsigned short u) {
    union { unsigned int i; float f; } x; x.i = ((unsigned int)u) << 16; return x.f;
}
__device__ inline unsigned short f2b(float f) {
    __hip_bfloat16 h = __float2bfloat16(f);
    return *reinterpret_cast<unsigned short*>(&h);
}

// ============================================================
// prep: fp32 -> bf16 operand conversion (s, Wcat rows, w_out->WOBT interleaved)
// ============================================================
__global__ __launch_bounds__(256) void prep_kernel(
    const float* __restrict__ s,
    const float* __restrict__ w_q,  const float* __restrict__ w_kv,
    const float* __restrict__ w_qp, const float* __restrict__ w_kvp,
    const float* __restrict__ w_out,
    unsigned short* __restrict__ SB, unsigned short* __restrict__ WB,
    unsigned short* __restrict__ WOBT)
{
    const long i4 = ((long)blockIdx.x * 256 + threadIdx.x) * 4;
    const float* src; unsigned short* dst; long off;
    if (i4 < 589824) {
        src = s + i4; dst = SB; off = i4;
    } else if (i4 < 1032192) {
        long e = i4 - 589824;
        int row = (int)(e / 384), c = (int)(e - (long)row * 384);
        const float* wsrc;
        if (row < 192)      wsrc = w_q   + (long)row * 384;
        else if (row < 576) wsrc = w_kv  + (long)(row - 192) * 384;
        else if (row < 720) wsrc = w_qp  + (long)(row - 576) * 384;
        else                wsrc = w_kvp + (long)(row - 720) * 384;
        src = wsrc + c; dst = WB; off = e;
    } else {
        long e = i4 - 1032192;           // element in w_out [384][576]
        int row = (int)(e / 576), c = (int)(e - (long)row * 576);
        src = w_out + e; dst = WOBT;
        off = (((long)(row >> 5) * 72 + (c >> 3)) * 32 + (row & 31)) * 8 + (c & 7);
    }
    float4 v = *(const float4*)src;
    short4v o;
    o[0] = (short)f2b(v.x); o[1] = (short)f2b(v.y);
    o[2] = (short)f2b(v.z); o[3] = (short)f2b(v.w);
    *(short4v*)(dst + off) = o;
}

// ============================================================
// fused: projection GEMM (MFMA, blocks 0..1727) + mask-bias pack (1728..2879)
// mask bias stored fp32 fragment-order, log2e-scaled.
// ============================================================
__global__ __launch_bounds__(64) void proj_mb_kernel(
    const unsigned short* __restrict__ SB, const unsigned short* __restrict__ WB,
    const float* __restrict__ b_q,  const float* __restrict__ b_kv,
    const float* __restrict__ b_qp, const float* __restrict__ b_kvp,
    const float* __restrict__ mask,
    float* __restrict__ PROJP, unsigned short* __restrict__ Qf,
    unsigned short* __restrict__ Kf, unsigned short* __restrict__ Vt,
    float* __restrict__ MBf)
{
    if (blockIdx.x >= 1728) {
        // ---- mask-bias pack (fp32, log2e-scaled) ----
        const int tile = blockIdx.x - 1728;   // b*576 + it*24 + jt
        const int jt = tile % 24;
        const int it = (tile / 24) % 24;
        const int b  = tile / 576;
        const int tt = threadIdx.x;           // == l
        const int i0 = it * 32, j0 = jt * 32;
        const float* mrow = mask + ((long)b * N_ + i0 + (tt & 31)) * N_
                          + j0 + (tt >> 5) * 4;
        float* outp = MBf + (long)tile * 1024 + tt * 16;
        #pragma unroll
        for (int g = 0; g < 4; ++g) {         // j-groups 0,8,16,24
            float4 mv = *(const float4*)(mrow + 8 * g);
            float4 ov = {INF2_ * (mv.x - 1.f), INF2_ * (mv.y - 1.f),
                         INF2_ * (mv.z - 1.f), INF2_ * (mv.w - 1.f)};
            *(float4*)(outp + g * 4) = ov;
        }
        return;
    }
    // ---- projection GEMM ----
    const int tile = blockIdx.x;          // 48 * 36
    const int tn = tile % 36, tm = tile / 36;
    const int r0 = tm * 32, c0 = tn * 32;
    const int l  = threadIdx.x;
    const int li = l & 31, hf = l >> 5;

    const unsigned short* ap = SB + (long)(r0 + li) * CN_ + hf * 8;
    const int col = c0 + li;
    const unsigned short* wb = WB + (long)col * CN_ + hf * 8;
    const float bias = (col < 192) ? b_q[col] : (col < 576) ? b_kv[col - 192]
                     : (col < 720) ? b_qp[col - 576] : b_kvp[col - 720];

    f32x16 acc = {};
    for (int k = 0; k < CN_; k += 32) {
        short8 a0 = *(const short8*)(ap + k);
        short8 a1 = *(const short8*)(ap + k + 16);
        short8 b0 = *(const short8*)(wb + k);
        short8 b1 = *(const short8*)(wb + k + 16);
        acc = __builtin_amdgcn_mfma_f32_32x32x16_bf16(a0, b0, acc, 0, 0, 0);
        acc = __builtin_amdgcn_mfma_f32_32x32x16_bf16(a1, b1, acc, 0, 0, 0);
    }
    const int row_b = r0 / N_;            // uniform: 768 % 32 == 0
    if (tn < 6) {                         // q tile (log2e/sqrt48 scale)
        const int hq = col >> 4, c = col & 15;
        const long qb = (long)(row_b * H_ + hq) * N_;
        #pragma unroll
        for (int r = 0; r < 16; ++r) {
            int row = r0 + (r & 3) + 8 * (r >> 2) + 4 * hf;
            int n = row - row_b * N_;
            Qf[(qb + n) * 32 + c] = f2b((acc[r] + bias) * QSCALE_);
        }
    } else if (tn < 18) {                 // kv tile, h = tn-6 uniform
        const int hkv = tn - 6;
        const long kb = (long)(row_b * H_ + hkv) * N_;
        const long vb = (long)(row_b * H_ + hkv) * 24;
        #pragma unroll
        for (int r = 0; r < 16; ++r) {
            int row = r0 + (r & 3) + 8 * (r >> 2) + 4 * hf;
            int n = row - row_b * N_;
            unsigned short v = f2b(acc[r] + bias);
            if (li < 16) Kf[(kb + n) * 32 + li] = v;
            else Vt[((vb + (n >> 5)) * 64 + (li - 16)) * 32 + (n & 31)] = v;
        }
    } else {                              // point tile -> PROJP fp32
        const int pc = col - 576;
        #pragma unroll
        for (int r = 0; r < 16; ++r) {
            int row = r0 + (r & 3) + 8 * (r >> 2) + 4 * hf;
            PROJP[(long)row * 576 + pc] = acc[r] + bias;
        }
    }
}

// ============================================================
// pack3: rotations only. One block (128 thr) per (b,n).
// hws carries log2e (affects qp slots AND kc consistently).
// ============================================================
__global__ __launch_bounds__(128) void pack3_kernel(
    const float* __restrict__ PROJP,
    const float* __restrict__ rot, const float* __restrict__ trans,
    const float* __restrict__ head_weights,
    unsigned short* __restrict__ Qf, unsigned short* __restrict__ Kf,
    unsigned short* __restrict__ Vt)
{
    __shared__ float pp[576];
    __shared__ float rt[12];
    __shared__ float hws[12];
    __shared__ float kp2[48];
    const int bn = blockIdx.x;
    const int t  = threadIdx.x;
    const float4* src = (const float4*)(PROJP + (long)bn * 576);
    for (int d = t; d < 144; d += 128) ((float4*)pp)[d] = src[d];
    if (t < 9) rt[t]     = rot[bn * 9 + t];
    if (t < 3) rt[9 + t] = trans[bn * 3 + t];
    if (t < 12) {
        float v  = head_weights[t];
        float sp = (v > 20.f) ? v : log1pf(expf(v));
        hws[t] = sp * HWSCALE_;           // softplus * sqrt(1/54) * log2e
    }
    __syncthreads();
    const int b = bn / N_, n = bn % N_;
    for (int e = t; e < 192; e += 128) {
        if (e < 48) {                     // qp point (h, p)
            int h = e >> 2, p = e & 3;
            float r0 = pp[     h * 4 + p];
            float r1 = pp[48 + h * 4 + p];
            float r2 = pp[96 + h * 4 + p];
            long base = ((long)(b * H_ + h) * N_ + n) * 32;
            #pragma unroll
            for (int x = 0; x < 3; ++x) {
                float o = rt[x*3]*r0 + rt[x*3+1]*r1 + rt[x*3+2]*r2 + rt[9+x];
                Qf[base + 16 + p * 3 + x] = f2b(o * hws[h]);
            }
        } else {                          // kvp point (h, pi)
            int idx = e - 48;
            int h = idx / 12, pi = idx - h * 12;
            float r0 = pp[144 +       h * 12 + pi];
            float r1 = pp[144 + 144 + h * 12 + pi];
            float r2 = pp[144 + 288 + h * 12 + pi];
            float o0 = rt[0]*r0 + rt[1]*r1 + rt[2]*r2 + rt[9];
            float o1 = rt[3]*r0 + rt[4]*r1 + rt[5]*r2 + rt[10];
            float o2 = rt[6]*r0 + rt[7]*r1 + rt[8]*r2 + rt[11];
            if (pi < 4) {
                long base = ((long)(b * H_ + h) * N_ + n) * 32;
                Kf[base + 16 + pi * 3 + 0] = f2b(o0);
                Kf[base + 16 + pi * 3 + 1] = f2b(o1);
                Kf[base + 16 + pi * 3 + 2] = f2b(o2);
                kp2[h * 4 + pi] = o0*o0 + o1*o1 + o2*o2;
            } else {
                int dd = 16 + (pi - 4) * 3;
                long vb = ((long)(b * H_ + h) * 24 + (n >> 5)) * 64;
                Vt[(vb + dd + 0) * 32 + (n & 31)] = f2b(o0);
                Vt[(vb + dd + 1) * 32 + (n & 31)] = f2b(o1);
                Vt[(vb + dd + 2) * 32 + (n & 31)] = f2b(o2);
            }
        }
    }
    __syncthreads();
    if (t < 12) {
        float s2 = kp2[t*4] + kp2[t*4+1] + kp2[t*4+2] + kp2[t*4+3];
        float kc = -0.5f * hws[t] * s2;   // log2e-scaled via hws
        long base = ((long)(b * H_ + t) * N_ + n) * 32;
        unsigned short hi = f2b(kc);
        Kf[base + 28] = hi;
        Kf[base + 29] = f2b(kc - b2f(hi));
        Kf[base + 30] = 0; Kf[base + 31] = 0;
        unsigned short one = f2b(1.f);
        Qf[base + 28] = one; Qf[base + 29] = one;
        Qf[base + 30] = 0;   Qf[base + 31] = 0;
    }
}

// ============================================================
// MFMA flash attention, exp2-domain softmax. Grid (b*12+h)*24+it, 512 thr.
// Merge writes o-part directly into CATT (chunks 0..23); points to OPg.
// ============================================================
__global__ __launch_bounds__(512) void attn2_kernel(
    const unsigned short* __restrict__ Qf, const unsigned short* __restrict__ Kf,
    const unsigned short* __restrict__ Vt, const float* __restrict__ MBf,
    unsigned short* __restrict__ CATT, unsigned short* __restrict__ OPg)
{
    __shared__ float red[8][64][23];
    const int blk = blockIdx.x;
    const int it = blk % 24;
    const int bh = blk / 24;
    const int hh = bh % 12;
    const int b  = bh / 12;
    const int t  = threadIdx.x;
    const int w  = t >> 6;
    const int l  = t & 63;
    const int li = l & 31;
    const int hf = l >> 5;
    const int i0 = it * 32;

    const unsigned short* qbase = Qf + ((long)bh * N_ + i0 + li) * 32 + hf * 8;
    short8 q0 = *(const short8*)(qbase);
    short8 q1 = *(const short8*)(qbase + 16);

    f32x16 acc0 = {};
    f32x16 acc1 = {};
    float m = -1e30f, lsum = 0.f;
    const unsigned short* vtb = Vt + (long)bh * 24 * 2048;
    const float* mbb = MBf + ((long)(b * 24 + it)) * 24 * 1024;

    #pragma unroll
    for (int ji = 0; ji < 3; ++ji) {
        const int jt = w * 3 + ji;
        const int j0 = jt * 32;
        // C-init: direct fp32 mask-bias loads (fragment order)
        const float* mbp = mbb + (long)jt * 1024 + l * 16;
        float4 f0 = *(const float4*)(mbp);
        float4 f1 = *(const float4*)(mbp + 4);
        float4 f2 = *(const float4*)(mbp + 8);
        float4 f3 = *(const float4*)(mbp + 12);
        f32x16 S;
        S[0]=f0.x;  S[1]=f0.y;  S[2]=f0.z;  S[3]=f0.w;
        S[4]=f1.x;  S[5]=f1.y;  S[6]=f1.z;  S[7]=f1.w;
        S[8]=f2.x;  S[9]=f2.y;  S[10]=f2.z; S[11]=f2.w;
        S[12]=f3.x; S[13]=f3.y; S[14]=f3.z; S[15]=f3.w;
        const unsigned short* kp = Kf + ((long)bh * N_ + j0 + li) * 32 + hf * 8;
        short8 k0 = *(const short8*)(kp);
        short8 k1 = *(const short8*)(kp + 16);
        S = __builtin_amdgcn_mfma_f32_32x32x16_bf16(k0, q0, S, 0, 0, 0);
        S = __builtin_amdgcn_mfma_f32_32x32x16_bf16(k1, q1, S, 0, 0, 0);
        // tree max (depth 4)
        float a0 = fmaxf(S[0],S[1]),  a1 = fmaxf(S[2],S[3]);
        float a2 = fmaxf(S[4],S[5]),  a3 = fmaxf(S[6],S[7]);
        float a4 = fmaxf(S[8],S[9]),  a5 = fmaxf(S[10],S[11]);
        float a6 = fmaxf(S[12],S[13]),a7 = fmaxf(S[14],S[15]);
        float b0 = fmaxf(fmaxf(a0,a1), fmaxf(a2,a3));
        float b1 = fmaxf(fmaxf(a4,a5), fmaxf(a6,a7));
        float mloc = fmaxf(b0, b1);
        {
            auto mm = __builtin_amdgcn_permlane32_swap(
                __float_as_int(mloc), __float_as_int(mloc), false, false);
            mloc = fmaxf(__int_as_float(mm[0]), __int_as_float(mm[1]));
        }
        float newm = fmaxf(m, mloc);
        float scale = EXP2F(m - newm);
        f32x16 p;
        #pragma unroll
        for (int r = 0; r < 16; ++r) p[r] = EXP2F(S[r] - newm);
        // tree sum
        float s0 = (p[0]+p[1]) + (p[2]+p[3]);
        float s1 = (p[4]+p[5]) + (p[6]+p[7]);
        float s2 = (p[8]+p[9]) + (p[10]+p[11]);
        float s3 = (p[12]+p[13]) + (p[14]+p[15]);
        float ps = (s0+s1) + (s2+s3);
        {
            auto ss = __builtin_amdgcn_permlane32_swap(
                __float_as_int(ps), __float_as_int(ps), false, false);
            ps = __int_as_float(ss[0]) + __int_as_float(ss[1]);
        }
        lsum = lsum * scale + ps;
        m = newm;
        #pragma unroll
        for (int r = 0; r < 16; ++r) acc0[r] *= scale;
        #pragma unroll
        for (int r = 0; r < 4; ++r)  acc1[r] *= scale;
        int c[8];
        #pragma unroll
        for (int r = 0; r < 8; ++r) {
            asm("v_cvt_pk_bf16_f32 %0, %1, %2" : "=v"(c[r]) : "v"(p[2*r]), "v"(p[2*r+1]));
        }
        union { int w4[4]; short8 v; } bf0, bf1;
        bf0.w4[0] = c[0]; bf0.w4[1] = c[1]; bf0.w4[2] = c[2]; bf0.w4[3] = c[3];
        bf1.w4[0] = c[4]; bf1.w4[1] = c[5]; bf1.w4[2] = c[6]; bf1.w4[3] = c[7];
        const unsigned short* tb  = vtb + jt * 2048;
        const unsigned short* vr0 = tb + li * 32 + hf * 4;
        const unsigned short* vr1 = tb + (32 + li) * 32 + hf * 4;
        union { short4v h[2]; short8 v; } v00, v01, v10, v11;
        v00.h[0] = *(const short4v*)(vr0);       v00.h[1] = *(const short4v*)(vr0 + 8);
        v01.h[0] = *(const short4v*)(vr1);       v01.h[1] = *(const short4v*)(vr1 + 8);
        v10.h[0] = *(const short4v*)(vr0 + 16);  v10.h[1] = *(const short4v*)(vr0 + 24);
        v11.h[0] = *(const short4v*)(vr1 + 16);  v11.h[1] = *(const short4v*)(vr1 + 24);
        acc0 = __builtin_amdgcn_mfma_f32_32x32x16_bf16(v00.v, bf0.v, acc0, 0, 0, 0);
        acc1 = __builtin_amdgcn_mfma_f32_32x32x16_bf16(v01.v, bf0.v, acc1, 0, 0, 0);
        acc0 = __builtin_amdgcn_mfma_f32_32x32x16_bf16(v10.v, bf1.v, acc0, 0, 0, 0);
        acc1 = __builtin_amdgcn_mfma_f32_32x32x16_bf16(v11.v, bf1.v, acc1, 0, 0, 0);
    }
    float* rd = &red[w][l][0];
    rd[0] = m; rd[1] = lsum;
    #pragma unroll
    for (int r = 0; r < 16; ++r) rd[2 + r]  = acc0[r];
    #pragma unroll
    for (int r = 0; r < 4; ++r)  rd[18 + r] = acc1[r];
    __syncthreads();
    {
        const int l2 = t & 63, g = t >> 6;
        const int li2 = l2 & 31, hf2 = l2 >> 5;
        float ms = -1e30f;
        #pragma unroll
        for (int ww = 0; ww < 8; ++ww) ms = fmaxf(ms, red[ww][l2][0]);
        float wt[8]; float lf = 0.f;
        #pragma unroll
        for (int ww = 0; ww < 8; ++ww) {
            wt[ww] = EXP2F(red[ww][l2][0] - ms);
            lf += wt[ww] * red[ww][l2][1];
        }
        float inv = 1.f / lf;
        const int n = i0 + li2;
        const long ctile = ((long)(b * 24 + it)) * 72 * 256 + li2 * 8;
        #pragma unroll
        for (int rr = 0; rr < 3; ++rr) {
            int r = g + rr * 8;
            if (r < 20) {
                float v = 0.f;
                #pragma unroll
                for (int ww = 0; ww < 8; ++ww) v += wt[ww] * red[ww][l2][2 + r];
                v *= inv;
                int d = (r < 16) ? ((r & 3) + 8 * (r >> 2) + 4 * hf2)
                                 : (32 + (r - 16) + 4 * hf2);
                unsigned short ov = f2b(v);
                if (d < 16) {
                    int c = hh * 16 + d;
                    CATT[ctile + (long)(c >> 3) * 256 + (c & 7)] = ov;
                } else {
                    OPg[((long)(b * N_ + n)) * 288 + hh * 24 + (d - 16)] = ov;
                }
            }
        }
    }
}

// ============================================================
// fused point-cat build + output GEMM. 144 blocks x 256 thr (4 waves).
// ============================================================
__global__ __launch_bounds__(256) void out_fused2(
    const unsigned short* __restrict__ CATT, const unsigned short* __restrict__ OPg,
    const float* __restrict__ rot, const float* __restrict__ trans,
    const unsigned short* __restrict__ WOBT, const float* __restrict__ b_out,
    float* __restrict__ out)
{
    __shared__ unsigned short op_s[32][288];
    __shared__ unsigned short catp[48][32][8];
    __shared__ float rt_s[32][12];
    const int blk = blockIdx.x;           // 48 * 3
    const int tm = blk / 3, tng = blk % 3;
    const int r0 = tm * 32;
    const int t  = threadIdx.x;

    for (int e = t; e < 32 * 36; e += 256) {
        int rr = e / 36, c8 = e - rr * 36;
        *(short8*)&op_s[rr][c8 * 8] = *(const short8*)(OPg + (long)(r0 + rr) * 288 + c8 * 8);
    }
    for (int e = t; e < 32 * 12; e += 256) {
        int rr = e / 12, c = e - rr * 12;
        rt_s[rr][c] = (c < 9) ? rot[(long)(r0 + rr) * 9 + c]
                              : trans[(long)(r0 + rr) * 3 + (c - 9)];
    }
    __syncthreads();
    for (int e = t; e < 3072; e += 256) {
        int rr = e / 96, pt = e - (e / 96) * 96;
        const float* rp = rt_s[rr];
        float g0 = b2f(op_s[rr][pt * 3 + 0]) - rp[9];
        float g1 = b2f(op_s[rr][pt * 3 + 1]) - rp[10];
        float g2 = b2f(op_s[rr][pt * 3 + 2]) - rp[11];
        float l0 = rp[0]*g0 + rp[3]*g1 + rp[6]*g2;
        float l1 = rp[1]*g0 + rp[4]*g1 + rp[7]*g2;
        float l2 = rp[2]*g0 + rp[5]*g1 + rp[8]*g2;
        int c;
        c = 192 + pt; catp[(c >> 3) - 24][rr][c & 7] = f2b(l0);
        c = 288 + pt; catp[(c >> 3) - 24][rr][c & 7] = f2b(l1);
        c = 384 + pt; catp[(c >> 3) - 24][rr][c & 7] = f2b(l2);
        c = 480 + pt; catp[(c >> 3) - 24][rr][c & 7] = f2b(sqrtf(l0*l0 + l1*l1 + l2*l2 + EPS_));
    }
    __syncthreads();
    const int wv = t >> 6, l = t & 63;
    const int li = l & 31, hf = l >> 5;
    const int tn = tng * 4 + wv;
    const unsigned short* ab = CATT + (long)tm * 72 * 256;
    const unsigned short* wb = WOBT + (long)tn * 72 * 256;
    f32x16 acc = {};
    for (int k = 0; k < 192; k += 32) {       // o-part: A from global CATT
        const int c = (k >> 3) + hf;
        short8 a0 = *(const short8*)(ab + (c * 32 + li) * 8);
        short8 a1 = *(const short8*)(ab + ((c + 2) * 32 + li) * 8);
        short8 b0 = *(const short8*)(wb + (c * 32 + li) * 8);
        short8 b1 = *(const short8*)(wb + ((c + 2) * 32 + li) * 8);
        acc = __builtin_amdgcn_mfma_f32_32x32x16_bf16(a0, b0, acc, 0, 0, 0);
        acc = __builtin_amdgcn_mfma_f32_32x32x16_bf16(a1, b1, acc, 0, 0, 0);
    }
    for (int k = 192; k < 576; k += 32) {     // point-part: A from LDS
        const int cg = (k >> 3) + hf;
        const int cl = cg - 24;
        short8 a0 = *(const short8*)&catp[cl][li][0];
        short8 a1 = *(const short8*)&catp[cl + 2][li][0];
        short8 b0 = *(const short8*)(wb + (cg * 32 + li) * 8);
        short8 b1 = *(const short8*)(wb + ((cg + 2) * 32 + li) * 8);
        acc = __builtin_amdgcn_mfma_f32_32x32x16_bf16(a0, b0, acc, 0, 0, 0);
        acc = __builtin_amdgcn_mfma_f32_32x32x16_bf16(a1, b1, acc, 0, 0, 0);
    }
    float bias = b_out[tn * 32 + li];
    #pragma unroll
    for (int r = 0; r < 16; ++r) {
        int row = r0 + (r & 3) + 8 * (r >> 2) + 4 * hf;
        out[(long)row * 384 + tn * 32 + li] = acc[r] + bias;
    }
}

// ============================================================
extern "C" void kernel_launch(void* const* d_in, const int* in_sizes, int n_in,
                              void* d_out, int out_size, void* d_ws, size_t ws_size,
                              hipStream_t stream) {
    const float* s            = (const float*)d_in[0];
    const float* rot          = (const float*)d_in[1];
    const float* trans        = (const float*)d_in[2];
    const float* pair_mask    = (const float*)d_in[3];
    const float* w_q          = (const float*)d_in[4];
    const float* b_q          = (const float*)d_in[5];
    const float* w_kv         = (const float*)d_in[6];
    const float* b_kv         = (const float*)d_in[7];
    const float* w_qp         = (const float*)d_in[8];
    const float* b_qp         = (const float*)d_in[9];
    const float* w_kvp        = (const float*)d_in[10];
    const float* b_kvp        = (const float*)d_in[11];
    const float* head_weights = (const float*)d_in[12];
    const float* w_out        = (const float*)d_in[13];
    const float* b_out        = (const float*)d_in[14];
    float* out = (float*)d_out;
    float* ws  = (float*)d_ws;

    float*          PROJP = ws + OFF_PROJP;
    unsigned short* OPg  = (unsigned short*)(ws + OFF_OP);
    unsigned short* CATT = (unsigned short*)(ws + OFF_CAT);
    unsigned short* Qf   = (unsigned short*)(ws + OFF_QF);
    unsigned short* Kf   = (unsigned short*)(ws + OFF_KF);
    unsigned short* Vt   = (unsigned short*)(ws + OFF_VT);
    unsigned short* SB   = (unsigned short*)(ws + OFF_SB);
    unsigned short* WB   = (unsigned short*)(ws + OFF_WB);
    unsigned short* WOBT = (unsigned short*)(ws + OFF_WOB);
    float*          MBf  = ws + OFF_MB;

    prep_kernel<<<1224, 256, 0, stream>>>(s, w_q, w_kv, w_qp, w_kvp, w_out,
                                          SB, WB, WOBT);
    proj_mb_kernel<<<48 * 36 + B_ * 24 * 24, 64, 0, stream>>>(
        SB, WB, b_q, b_kv, b_qp, b_kvp, pair_mask, PROJP, Qf, Kf, Vt, MBf);
    pack3_kernel<<<B_ * N_, 128, 0, stream>>>(PROJP, rot, trans, head_weights,
                                              Qf, Kf, Vt);
    attn2_kernel<<<B_ * H_ * 24, 512, 0, stream>>>(Qf, Kf, Vt, MBf, CATT, OPg);
    out_fused2<<<48 * 3, 256, 0, stream>>>(CATT, OPg, rot, trans, WOBT, b_out, out);
}

// Round 17
// 56.675 us; speedup vs baseline: 1.0899x; 1.0899x over previous
//
#include <hip/hip_runtime.h>
#include <hip/hip_bf16.h>
#include <math.h>

typedef __attribute__((ext_vector_type(4)))  short short4v;
typedef __attribute__((ext_vector_type(8)))  short short8;
typedef __attribute__((ext_vector_type(16))) float f32x16;

#define B_   2
#define N_   768
#define CN_  384
#define H_   12
#define INF_ 100000.0f
#define EPS_ 1e-7f

// ---------------- workspace layout (f32-slot offsets) ----------------
// PROJP f32 [1536][576]       at 0        (point-proj columns + bias; dead after pack3)
// OPg bf16 [1536][288]        at 1032192
// CATT bf16 [48][72][32][8]   at 1253376  (chunk-interleaved; chunks 0..23 = o-part,
//     written directly by attn2's merge; chunks 24..71 never touched in global)
// Qf  bf16 [24][768][32]      at 1769472
// Kf  bf16 [24][768][32]      at 2064384
// VtT bf16 [24][24][64][32]   at 2359296  (tile-interleaved; d rows 40..63
//     never written: garbage confined to discarded acc1 regs 4..15)
// SB  bf16 [1536][384]        at 2949120
// WB  bf16 [1152][384]        at 3244032
// WOBT bf16 [12][72][32][8]   at 3465216  (chunk-interleaved w_out)
// MB  bf16 [2][24][24][64][16] at 3575808
#define OFF_PROJP 0
#define OFF_OP    1032192
#define OFF_CAT   1253376
#define OFF_QF    1769472
#define OFF_KF    2064384
#define OFF_VT    2359296
#define OFF_SB    2949120
#define OFF_WB    3244032
#define OFF_WOB   3465216
#define OFF_MB    3575808

__device__ inline float b2f(unsigned short u) {
    union { unsigned int i; float f; } x; x.i = ((unsigned int)u) << 16; return x.f;
}
__device__ inline unsigned short f2b(float f) {
    __hip_bfloat16 h = __float2bfloat16(f);
    return *reinterpret_cast<unsigned short*>(&h);
}

// ============================================================
// prep: fp32 -> bf16 operand conversion (s, Wcat rows, w_out->WOBT interleaved)
// ============================================================
__global__ __launch_bounds__(256) void prep_kernel(
    const float* __restrict__ s,
    const float* __restrict__ w_q,  const float* __restrict__ w_kv,
    const float* __restrict__ w_qp, const float* __restrict__ w_kvp,
    const float* __restrict__ w_out,
    unsigned short* __restrict__ SB, unsigned short* __restrict__ WB,
    unsigned short* __restrict__ WOBT)
{
    const long i4 = ((long)blockIdx.x * 256 + threadIdx.x) * 4;
    const float* src; unsigned short* dst; long off;
    if (i4 < 589824) {
        src = s + i4; dst = SB; off = i4;
    } else if (i4 < 1032192) {
        long e = i4 - 589824;
        int row = (int)(e / 384), c = (int)(e - (long)row * 384);
        const float* wsrc;
        if (row < 192)      wsrc = w_q   + (long)row * 384;
        else if (row < 576) wsrc = w_kv  + (long)(row - 192) * 384;
        else if (row < 720) wsrc = w_qp  + (long)(row - 576) * 384;
        else                wsrc = w_kvp + (long)(row - 720) * 384;
        src = wsrc + c; dst = WB; off = e;
    } else {
        long e = i4 - 1032192;           // element in w_out [384][576]
        int row = (int)(e / 576), c = (int)(e - (long)row * 576);
        src = w_out + e; dst = WOBT;
        off = (((long)(row >> 5) * 72 + (c >> 3)) * 32 + (row & 31)) * 8 + (c & 7);
    }
    float4 v = *(const float4*)src;
    short4v o;
    o[0] = (short)f2b(v.x); o[1] = (short)f2b(v.y);
    o[2] = (short)f2b(v.z); o[3] = (short)f2b(v.w);
    *(short4v*)(dst + off) = o;
}

// ============================================================
// fused: projection GEMM (MFMA, blocks 0..1727) + mask-bias pack (1728..2879)
// ============================================================
__global__ __launch_bounds__(64) void proj_mb_kernel(
    const unsigned short* __restrict__ SB, const unsigned short* __restrict__ WB,
    const float* __restrict__ b_q,  const float* __restrict__ b_kv,
    const float* __restrict__ b_qp, const float* __restrict__ b_kvp,
    const float* __restrict__ mask,
    float* __restrict__ PROJP, unsigned short* __restrict__ Qf,
    unsigned short* __restrict__ Kf, unsigned short* __restrict__ Vt,
    unsigned short* __restrict__ MB)
{
    if (blockIdx.x >= 1728) {
        // ---- mask-bias pack ----
        const int tile = blockIdx.x - 1728;   // b*576 + it*24 + jt
        const int jt = tile % 24;
        const int it = (tile / 24) % 24;
        const int b  = tile / 576;
        const int tt = threadIdx.x;           // == l
        const int i0 = it * 32, j0 = jt * 32;
        const float* mrow = mask + ((long)b * N_ + i0 + (tt & 31)) * N_
                          + j0 + (tt >> 5) * 4;
        union { unsigned short u[16]; short8 v[2]; } o;
        #pragma unroll
        for (int g = 0; g < 4; ++g) {         // j-groups 0,8,16,24
            float4 mv = *(const float4*)(mrow + 8 * g);
            o.u[g*4+0] = f2b(INF_ * (mv.x - 1.f));
            o.u[g*4+1] = f2b(INF_ * (mv.y - 1.f));
            o.u[g*4+2] = f2b(INF_ * (mv.z - 1.f));
            o.u[g*4+3] = f2b(INF_ * (mv.w - 1.f));
        }
        unsigned short* outp = MB + (long)tile * 1024 + tt * 16;
        *(short8*)(outp)     = o.v[0];
        *(short8*)(outp + 8) = o.v[1];
        return;
    }
    // ---- projection GEMM ----
    const int tile = blockIdx.x;          // 48 * 36
    const int tn = tile % 36, tm = tile / 36;
    const int r0 = tm * 32, c0 = tn * 32;
    const int l  = threadIdx.x;
    const int li = l & 31, hf = l >> 5;

    const unsigned short* ap = SB + (long)(r0 + li) * CN_ + hf * 8;
    const int col = c0 + li;
    const unsigned short* wb = WB + (long)col * CN_ + hf * 8;
    const float bias = (col < 192) ? b_q[col] : (col < 576) ? b_kv[col - 192]
                     : (col < 720) ? b_qp[col - 576] : b_kvp[col - 720];

    f32x16 acc = {};
    for (int k = 0; k < CN_; k += 32) {
        short8 a0 = *(const short8*)(ap + k);
        short8 a1 = *(const short8*)(ap + k + 16);
        short8 b0 = *(const short8*)(wb + k);
        short8 b1 = *(const short8*)(wb + k + 16);
        acc = __builtin_amdgcn_mfma_f32_32x32x16_bf16(a0, b0, acc, 0, 0, 0);
        acc = __builtin_amdgcn_mfma_f32_32x32x16_bf16(a1, b1, acc, 0, 0, 0);
    }
    const int row_b = r0 / N_;            // uniform: 768 % 32 == 0
    if (tn < 6) {                         // q tile
        const int hq = col >> 4, c = col & 15;
        const long qb = (long)(row_b * H_ + hq) * N_;
        #pragma unroll
        for (int r = 0; r < 16; ++r) {
            int row = r0 + (r & 3) + 8 * (r >> 2) + 4 * hf;
            int n = row - row_b * N_;
            Qf[(qb + n) * 32 + c] = f2b((acc[r] + bias) * 0.144337567297406f);
        }
    } else if (tn < 18) {                 // kv tile, h = tn-6 uniform
        const int hkv = tn - 6;
        const long kb = (long)(row_b * H_ + hkv) * N_;
        const long vb = (long)(row_b * H_ + hkv) * 24;
        #pragma unroll
        for (int r = 0; r < 16; ++r) {
            int row = r0 + (r & 3) + 8 * (r >> 2) + 4 * hf;
            int n = row - row_b * N_;
            unsigned short v = f2b(acc[r] + bias);
            if (li < 16) Kf[(kb + n) * 32 + li] = v;
            else Vt[((vb + (n >> 5)) * 64 + (li - 16)) * 32 + (n & 31)] = v;
        }
    } else {                              // point tile -> PROJP fp32
        const int pc = col - 576;
        #pragma unroll
        for (int r = 0; r < 16; ++r) {
            int row = r0 + (r & 3) + 8 * (r >> 2) + 4 * hf;
            PROJP[(long)row * 576 + pc] = acc[r] + bias;
        }
    }
}

// ============================================================
// pack3: rotations only. One block (128 thr) per (b,n).
// ============================================================
__global__ __launch_bounds__(128) void pack3_kernel(
    const float* __restrict__ PROJP,
    const float* __restrict__ rot, const float* __restrict__ trans,
    const float* __restrict__ head_weights,
    unsigned short* __restrict__ Qf, unsigned short* __restrict__ Kf,
    unsigned short* __restrict__ Vt)
{
    __shared__ float pp[576];
    __shared__ float rt[12];
    __shared__ float hws[12];
    __shared__ float kp2[48];
    const int bn = blockIdx.x;
    const int t  = threadIdx.x;
    const float4* src = (const float4*)(PROJP + (long)bn * 576);
    for (int d = t; d < 144; d += 128) ((float4*)pp)[d] = src[d];
    if (t < 9) rt[t]     = rot[bn * 9 + t];
    if (t < 3) rt[9 + t] = trans[bn * 3 + t];
    if (t < 12) {
        float v  = head_weights[t];
        float sp = (v > 20.f) ? v : log1pf(expf(v));
        hws[t] = sp * 0.13608276348795434f;  // softplus * sqrt(1/54)
    }
    __syncthreads();
    const int b = bn / N_, n = bn % N_;
    for (int e = t; e < 192; e += 128) {
        if (e < 48) {                     // qp point (h, p)
            int h = e >> 2, p = e & 3;
            float r0 = pp[     h * 4 + p];
            float r1 = pp[48 + h * 4 + p];
            float r2 = pp[96 + h * 4 + p];
            long base = ((long)(b * H_ + h) * N_ + n) * 32;
            #pragma unroll
            for (int x = 0; x < 3; ++x) {
                float o = rt[x*3]*r0 + rt[x*3+1]*r1 + rt[x*3+2]*r2 + rt[9+x];
                Qf[base + 16 + p * 3 + x] = f2b(o * hws[h]);
            }
        } else {                          // kvp point (h, pi)
            int idx = e - 48;
            int h = idx / 12, pi = idx - h * 12;
            float r0 = pp[144 +       h * 12 + pi];
            float r1 = pp[144 + 144 + h * 12 + pi];
            float r2 = pp[144 + 288 + h * 12 + pi];
            float o0 = rt[0]*r0 + rt[1]*r1 + rt[2]*r2 + rt[9];
            float o1 = rt[3]*r0 + rt[4]*r1 + rt[5]*r2 + rt[10];
            float o2 = rt[6]*r0 + rt[7]*r1 + rt[8]*r2 + rt[11];
            if (pi < 4) {
                long base = ((long)(b * H_ + h) * N_ + n) * 32;
                Kf[base + 16 + pi * 3 + 0] = f2b(o0);
                Kf[base + 16 + pi * 3 + 1] = f2b(o1);
                Kf[base + 16 + pi * 3 + 2] = f2b(o2);
                kp2[h * 4 + pi] = o0*o0 + o1*o1 + o2*o2;
            } else {
                int dd = 16 + (pi - 4) * 3;
                long vb = ((long)(b * H_ + h) * 24 + (n >> 5)) * 64;
                Vt[(vb + dd + 0) * 32 + (n & 31)] = f2b(o0);
                Vt[(vb + dd + 1) * 32 + (n & 31)] = f2b(o1);
                Vt[(vb + dd + 2) * 32 + (n & 31)] = f2b(o2);
            }
        }
    }
    __syncthreads();
    if (t < 12) {
        float s2 = kp2[t*4] + kp2[t*4+1] + kp2[t*4+2] + kp2[t*4+3];
        float kc = -0.5f * hws[t] * s2;
        long base = ((long)(b * H_ + t) * N_ + n) * 32;
        unsigned short hi = f2b(kc);
        Kf[base + 28] = hi;
        Kf[base + 29] = f2b(kc - b2f(hi));
        Kf[base + 30] = 0; Kf[base + 31] = 0;
        unsigned short one = f2b(1.f);
        Qf[base + 28] = one; Qf[base + 29] = one;
        Qf[base + 30] = 0;   Qf[base + 31] = 0;
    }
}

// ============================================================
// MFMA flash attention. Grid (b*12+h)*24+it, 512 threads = 8 waves.
// Merge writes o-part DIRECTLY into CATT chunk-interleaved (chunks 0..23);
// point-part still goes to OPg. (b*N_+i0)>>5 == b*24+it.
// ============================================================
__global__ __launch_bounds__(512) void attn2_kernel(
    const unsigned short* __restrict__ Qf, const unsigned short* __restrict__ Kf,
    const unsigned short* __restrict__ Vt, const unsigned short* __restrict__ MB,
    unsigned short* __restrict__ CATT, unsigned short* __restrict__ OPg)
{
    __shared__ float red[8][64][23];   // 23: odd stride -> conflict-free merge
    const int blk = blockIdx.x;
    const int it = blk % 24;
    const int bh = blk / 24;
    const int hh = bh % 12;
    const int b  = bh / 12;
    const int t  = threadIdx.x;
    const int w  = t >> 6;
    const int l  = t & 63;
    const int li = l & 31;
    const int hf = l >> 5;
    const int i0 = it * 32;

    const unsigned short* qbase = Qf + ((long)bh * N_ + i0 + li) * 32 + hf * 8;
    short8 q0 = *(const short8*)(qbase);
    short8 q1 = *(const short8*)(qbase + 16);

    f32x16 acc0 = {};
    f32x16 acc1 = {};
    float m = -1e30f, lsum = 0.f;
    const unsigned short* vtb = Vt + (long)bh * 24 * 2048;
    const unsigned short* mbb = MB + ((long)(b * 24 + it)) * 24 * 1024;

    for (int jt = w * 3; jt < w * 3 + 3; ++jt) {
        const int j0 = jt * 32;
        const unsigned short* mbp = mbb + (long)jt * 1024 + l * 16;
        short8 mb0 = *(const short8*)(mbp);
        short8 mb1 = *(const short8*)(mbp + 8);
        f32x16 S;
        #pragma unroll
        for (int r = 0; r < 8; ++r) S[r]     = b2f((unsigned short)mb0[r]);
        #pragma unroll
        for (int r = 0; r < 8; ++r) S[8 + r] = b2f((unsigned short)mb1[r]);
        const unsigned short* kp = Kf + ((long)bh * N_ + j0 + li) * 32 + hf * 8;
        short8 k0 = *(const short8*)(kp);
        short8 k1 = *(const short8*)(kp + 16);
        S = __builtin_amdgcn_mfma_f32_32x32x16_bf16(k0, q0, S, 0, 0, 0);
        S = __builtin_amdgcn_mfma_f32_32x32x16_bf16(k1, q1, S, 0, 0, 0);
        float mloc = S[0];
        #pragma unroll
        for (int r = 1; r < 16; ++r) mloc = fmaxf(mloc, S[r]);
        {
            auto mm = __builtin_amdgcn_permlane32_swap(
                __float_as_int(mloc), __float_as_int(mloc), false, false);
            mloc = fmaxf(__int_as_float(mm[0]), __int_as_float(mm[1]));
        }
        float newm = fmaxf(m, mloc);
        float scale = __expf(m - newm);
        float ps = 0.f;
        f32x16 p;
        #pragma unroll
        for (int r = 0; r < 16; ++r) { p[r] = __expf(S[r] - newm); ps += p[r]; }
        {
            auto ss = __builtin_amdgcn_permlane32_swap(
                __float_as_int(ps), __float_as_int(ps), false, false);
            ps = __int_as_float(ss[0]) + __int_as_float(ss[1]);
        }
        lsum = lsum * scale + ps;
        m = newm;
        #pragma unroll
        for (int r = 0; r < 16; ++r) acc0[r] *= scale;
        #pragma unroll
        for (int r = 0; r < 4; ++r)  acc1[r] *= scale;
        int c[8];
        #pragma unroll
        for (int r = 0; r < 8; ++r) {
            asm("v_cvt_pk_bf16_f32 %0, %1, %2" : "=v"(c[r]) : "v"(p[2*r]), "v"(p[2*r+1]));
        }
        union { int w4[4]; short8 v; } bf0, bf1;
        bf0.w4[0] = c[0]; bf0.w4[1] = c[1]; bf0.w4[2] = c[2]; bf0.w4[3] = c[3];
        bf1.w4[0] = c[4]; bf1.w4[1] = c[5]; bf1.w4[2] = c[6]; bf1.w4[3] = c[7];
        const unsigned short* tb  = vtb + jt * 2048;
        const unsigned short* vr0 = tb + li * 32 + hf * 4;
        const unsigned short* vr1 = tb + (32 + li) * 32 + hf * 4;
        union { short4v h[2]; short8 v; } v00, v01, v10, v11;
        v00.h[0] = *(const short4v*)(vr0);       v00.h[1] = *(const short4v*)(vr0 + 8);
        v01.h[0] = *(const short4v*)(vr1);       v01.h[1] = *(const short4v*)(vr1 + 8);
        v10.h[0] = *(const short4v*)(vr0 + 16);  v10.h[1] = *(const short4v*)(vr0 + 24);
        v11.h[0] = *(const short4v*)(vr1 + 16);  v11.h[1] = *(const short4v*)(vr1 + 24);
        acc0 = __builtin_amdgcn_mfma_f32_32x32x16_bf16(v00.v, bf0.v, acc0, 0, 0, 0);
        acc1 = __builtin_amdgcn_mfma_f32_32x32x16_bf16(v01.v, bf0.v, acc1, 0, 0, 0);
        acc0 = __builtin_amdgcn_mfma_f32_32x32x16_bf16(v10.v, bf1.v, acc0, 0, 0, 0);
        acc1 = __builtin_amdgcn_mfma_f32_32x32x16_bf16(v11.v, bf1.v, acc1, 0, 0, 0);
    }
    float* rd = &red[w][l][0];
    rd[0] = m; rd[1] = lsum;
    #pragma unroll
    for (int r = 0; r < 16; ++r) rd[2 + r]  = acc0[r];
    #pragma unroll
    for (int r = 0; r < 4; ++r)  rd[18 + r] = acc1[r];
    __syncthreads();
    {
        const int l2 = t & 63, g = t >> 6;
        const int li2 = l2 & 31, hf2 = l2 >> 5;
        float ms = -1e30f;
        #pragma unroll
        for (int ww = 0; ww < 8; ++ww) ms = fmaxf(ms, red[ww][l2][0]);
        float wt[8]; float lf = 0.f;
        #pragma unroll
        for (int ww = 0; ww < 8; ++ww) {
            wt[ww] = __expf(red[ww][l2][0] - ms);
            lf += wt[ww] * red[ww][l2][1];
        }
        float inv = 1.f / lf;
        const int n = i0 + li2;
        const long ctile = ((long)(b * 24 + it)) * 72 * 256 + li2 * 8;
        #pragma unroll
        for (int rr = 0; rr < 3; ++rr) {
            int r = g + rr * 8;
            if (r < 20) {
                float v = 0.f;
                #pragma unroll
                for (int ww = 0; ww < 8; ++ww) v += wt[ww] * red[ww][l2][2 + r];
                v *= inv;
                int d = (r < 16) ? ((r & 3) + 8 * (r >> 2) + 4 * hf2)
                                 : (32 + (r - 16) + 4 * hf2);
                unsigned short ov = f2b(v);
                if (d < 16) {
                    int c = hh * 16 + d;
                    CATT[ctile + (long)(c >> 3) * 256 + (c & 7)] = ov;
                } else {
                    OPg[((long)(b * N_ + n)) * 288 + hh * 24 + (d - 16)] = ov;
                }
            }
        }
    }
}

// ============================================================
// fused point-cat build + output GEMM. 144 blocks x 256 thr (4 waves).
// Block (tm, tng): rows r0=tm*32, waves handle tn = tng*4 + wv.
// Phase A: stage OPg tile + rot/trans.  Phase B: 3072 rotations flat.
// Phase C: k<192 A-chunks from CATT global (o-part, written by attn2);
//          k>=192 A-chunks from LDS catp. All reads lane-contiguous.
// ============================================================
__global__ __launch_bounds__(256) void out_fused2(
    const unsigned short* __restrict__ CATT, const unsigned short* __restrict__ OPg,
    const float* __restrict__ rot, const float* __restrict__ trans,
    const unsigned short* __restrict__ WOBT, const float* __restrict__ b_out,
    float* __restrict__ out)
{
    __shared__ unsigned short op_s[32][288];
    __shared__ unsigned short catp[48][32][8];
    __shared__ float rt_s[32][12];
    const int blk = blockIdx.x;           // 48 * 3
    const int tm = blk / 3, tng = blk % 3;
    const int r0 = tm * 32;
    const int t  = threadIdx.x;

    for (int e = t; e < 32 * 36; e += 256) {
        int rr = e / 36, c8 = e - rr * 36;
        *(short8*)&op_s[rr][c8 * 8] = *(const short8*)(OPg + (long)(r0 + rr) * 288 + c8 * 8);
    }
    for (int e = t; e < 32 * 12; e += 256) {
        int rr = e / 12, c = e - rr * 12;
        rt_s[rr][c] = (c < 9) ? rot[(long)(r0 + rr) * 9 + c]
                              : trans[(long)(r0 + rr) * 3 + (c - 9)];
    }
    __syncthreads();
    for (int e = t; e < 3072; e += 256) {
        int rr = e / 96, pt = e - (e / 96) * 96;
        const float* rp = rt_s[rr];
        float g0 = b2f(op_s[rr][pt * 3 + 0]) - rp[9];
        float g1 = b2f(op_s[rr][pt * 3 + 1]) - rp[10];
        float g2 = b2f(op_s[rr][pt * 3 + 2]) - rp[11];
        float l0 = rp[0]*g0 + rp[3]*g1 + rp[6]*g2;
        float l1 = rp[1]*g0 + rp[4]*g1 + rp[7]*g2;
        float l2 = rp[2]*g0 + rp[5]*g1 + rp[8]*g2;
        int c;
        c = 192 + pt; catp[(c >> 3) - 24][rr][c & 7] = f2b(l0);
        c = 288 + pt; catp[(c >> 3) - 24][rr][c & 7] = f2b(l1);
        c = 384 + pt; catp[(c >> 3) - 24][rr][c & 7] = f2b(l2);
        c = 480 + pt; catp[(c >> 3) - 24][rr][c & 7] = f2b(sqrtf(l0*l0 + l1*l1 + l2*l2 + EPS_));
    }
    __syncthreads();
    const int wv = t >> 6, l = t & 63;
    const int li = l & 31, hf = l >> 5;
    const int tn = tng * 4 + wv;
    const unsigned short* ab = CATT + (long)tm * 72 * 256;
    const unsigned short* wb = WOBT + (long)tn * 72 * 256;
    f32x16 acc = {};
    for (int k = 0; k < 192; k += 32) {       // o-part: A from global CATT
        const int c = (k >> 3) + hf;
        short8 a0 = *(const short8*)(ab + (c * 32 + li) * 8);
        short8 a1 = *(const short8*)(ab + ((c + 2) * 32 + li) * 8);
        short8 b0 = *(const short8*)(wb + (c * 32 + li) * 8);
        short8 b1 = *(const short8*)(wb + ((c + 2) * 32 + li) * 8);
        acc = __builtin_amdgcn_mfma_f32_32x32x16_bf16(a0, b0, acc, 0, 0, 0);
        acc = __builtin_amdgcn_mfma_f32_32x32x16_bf16(a1, b1, acc, 0, 0, 0);
    }
    for (int k = 192; k < 576; k += 32) {     // point-part: A from LDS
        const int cg = (k >> 3) + hf;
        const int cl = cg - 24;
        short8 a0 = *(const short8*)&catp[cl][li][0];
        short8 a1 = *(const short8*)&catp[cl + 2][li][0];
        short8 b0 = *(const short8*)(wb + (cg * 32 + li) * 8);
        short8 b1 = *(const short8*)(wb + ((cg + 2) * 32 + li) * 8);
        acc = __builtin_amdgcn_mfma_f32_32x32x16_bf16(a0, b0, acc, 0, 0, 0);
        acc = __builtin_amdgcn_mfma_f32_32x32x16_bf16(a1, b1, acc, 0, 0, 0);
    }
    float bias = b_out[tn * 32 + li];
    #pragma unroll
    for (int r = 0; r < 16; ++r) {
        int row = r0 + (r & 3) + 8 * (r >> 2) + 4 * hf;
        out[(long)row * 384 + tn * 32 + li] = acc[r] + bias;
    }
}

// ============================================================
extern "C" void kernel_launch(void* const* d_in, const int* in_sizes, int n_in,
                              void* d_out, int out_size, void* d_ws, size_t ws_size,
                              hipStream_t stream) {
    const float* s            = (const float*)d_in[0];
    const float* rot          = (const float*)d_in[1];
    const float* trans        = (const float*)d_in[2];
    const float* pair_mask    = (const float*)d_in[3];
    const float* w_q          = (const float*)d_in[4];
    const float* b_q          = (const float*)d_in[5];
    const float* w_kv         = (const float*)d_in[6];
    const float* b_kv         = (const float*)d_in[7];
    const float* w_qp         = (const float*)d_in[8];
    const float* b_qp         = (const float*)d_in[9];
    const float* w_kvp        = (const float*)d_in[10];
    const float* b_kvp        = (const float*)d_in[11];
    const float* head_weights = (const float*)d_in[12];
    const float* w_out        = (const float*)d_in[13];
    const float* b_out        = (const float*)d_in[14];
    float* out = (float*)d_out;
    float* ws  = (float*)d_ws;

    float*          PROJP = ws + OFF_PROJP;
    unsigned short* OPg  = (unsigned short*)(ws + OFF_OP);
    unsigned short* CATT = (unsigned short*)(ws + OFF_CAT);
    unsigned short* Qf   = (unsigned short*)(ws + OFF_QF);
    unsigned short* Kf   = (unsigned short*)(ws + OFF_KF);
    unsigned short* Vt   = (unsigned short*)(ws + OFF_VT);
    unsigned short* SB   = (unsigned short*)(ws + OFF_SB);
    unsigned short* WB   = (unsigned short*)(ws + OFF_WB);
    unsigned short* WOBT = (unsigned short*)(ws + OFF_WOB);
    unsigned short* MBp  = (unsigned short*)(ws + OFF_MB);

    prep_kernel<<<1224, 256, 0, stream>>>(s, w_q, w_kv, w_qp, w_kvp, w_out,
                                          SB, WB, WOBT);
    proj_mb_kernel<<<48 * 36 + B_ * 24 * 24, 64, 0, stream>>>(
        SB, WB, b_q, b_kv, b_qp, b_kvp, pair_mask, PROJP, Qf, Kf, Vt, MBp);
    pack3_kernel<<<B_ * N_, 128, 0, stream>>>(PROJP, rot, trans, head_weights,
                                              Qf, Kf, Vt);
    attn2_kernel<<<B_ * H_ * 24, 512, 0, stream>>>(Qf, Kf, Vt, MBp, CATT, OPg);
    out_fused2<<<48 * 3, 256, 0, stream>>>(CATT, OPg, rot, trans, WOBT, b_out, out);
}